// Round 17
// baseline (372.890 us; speedup 1.0000x reference)
//
#include <hip/hip_runtime.h>
#include <hip/hip_bf16.h>
#include <math.h>

#define Timg 131072            // 8 * 128 * 128 tokens after merge
#define SCALE 0.17677669529663689f

typedef __attribute__((ext_vector_type(8))) short frag8;
typedef __attribute__((ext_vector_type(4))) float f32x4;
typedef __attribute__((ext_vector_type(4))) unsigned int u32x4;

__device__ inline float bf2f(unsigned short u) {
    union { unsigned int i; float f; } v; v.i = ((unsigned int)u) << 16; return v.f;
}
// native cast -> compiler emits the hardware bf16 convert with full scheduling freedom
__device__ inline unsigned short f2bf(float f) {
    __hip_bfloat16 h = __float2bfloat16(f);
    return *reinterpret_cast<unsigned short*>(&h);
}
__device__ inline unsigned int pk2(float lo, float hi) {
    return ((unsigned int)f2bf(hi) << 16) | (unsigned int)f2bf(lo);
}
__device__ inline float gelu_f(float x) {
    float u = x * x;
    float z = x * fmaf(u, 0.044715f, 1.0f);                 // x + 0.044715 x^3
    float e = __builtin_amdgcn_exp2f(-2.3025851f * z);      // exp(-1.5957691*z)
    return x * __builtin_amdgcn_rcpf(1.f + e);
}

// ---------------------------------------------------------------- all weight converts in ONE launch
struct WcvtAll {
    const float* src[9];
    unsigned short* dst[9];
    int R[9];
    int C[9];
    int qrows[9];
};
__global__ __launch_bounds__(256) void k_wcvt_all(WcvtAll wa, float s)
{
    int wsel = blockIdx.y;
    int R = wa.R[wsel], C = wa.C[wsel];
    int idx = blockIdx.x * 256 + threadIdx.x;
    if (idx >= R * C) return;
    int r = idx / C, c = idx % C;
    float v = wa.src[wsel][idx];
    if (c < wa.qrows[wsel]) v *= s;
    wa.dst[wsel][(size_t)c * R + r] = f2bf(v);
}

// ---------------------------------------------------------------- K1: patch merge + MFMA GEMM (K=256 -> N=128), BM=64
#define LDA_PM 264
__global__ __launch_bounds__(256) void k_patchmerge(
    const float* __restrict__ x, const unsigned short* __restrict__ Wmt,
    const float* __restrict__ bm, float* __restrict__ t)
{
    __shared__ unsigned short A[64 * LDA_PM];
    int blk = blockIdx.x;              // 2048 = 8b x 128h x 2 halves
    int b   = blk >> 8;
    int rem = blk & 255;
    int h   = rem >> 1;
    int w0  = (rem & 1) * 64;
    int tid = threadIdx.x;
    {
        int row = tid >> 1, half = tid & 1;
        int c = row >> 1, ki = row & 1;
        const float* src = x + (((size_t)(b*64 + c))*256 + (size_t)(2*h + ki))*256 + 2*w0 + half*64;
        int base = c*4 + ki*2;
        #pragma unroll
        for (int q = 0; q < 16; ++q) {
            float4 v = *reinterpret_cast<const float4*>(src + q*4);
            int tk0 = (half*64 + q*4) >> 1;
            *reinterpret_cast<unsigned int*>(&A[ tk0     * LDA_PM + base]) = pk2(v.x, v.y);
            *reinterpret_cast<unsigned int*>(&A[(tk0 + 1)* LDA_PM + base]) = pk2(v.z, v.w);
        }
    }
    __syncthreads();
    int lane = tid & 63, w = tid >> 6;
    int lr = lane & 15, lg = lane >> 4;
    size_t tok0 = (size_t)blk * 64;
    #pragma unroll
    for (int nt = 0; nt < 2; ++nt) {
        int n0 = (w*2 + nt) * 16;
        f32x4 acc[4] = {};
        #pragma unroll
        for (int ks = 0; ks < 8; ++ks) {
            frag8 bfr = *reinterpret_cast<const frag8*>(Wmt + (size_t)(n0 + lr)*256 + ks*32 + lg*8);
            #pragma unroll
            for (int m = 0; m < 4; ++m) {
                frag8 af = *reinterpret_cast<const frag8*>(&A[(m*16 + lr)*LDA_PM + ks*32 + lg*8]);
                acc[m] = __builtin_amdgcn_mfma_f32_16x16x32_bf16(af, bfr, acc[m], 0, 0, 0);
            }
        }
        #pragma unroll
        for (int m = 0; m < 4; ++m)
            #pragma unroll
            for (int r = 0; r < 4; ++r) {
                int rowl = m*16 + lg*4 + r;
                int col  = n0 + lr;
                t[(tok0 + rowl)*128 + col] = acc[m][r] + bm[col];
            }
    }
}

// ---------------------------------------------------------------- K2: mega-kernel: one window (64 tokens) per block.
#define LDQK 200   // QK rows [64][200]: Q cols 0..95 (pre-scaled via Wq), K cols 96..191
#define LDVT 72    // Vt [96][72]  (V transposed: d-major)
#define LDP  72    // P  [64][72]  (softmax probs, wave-private rows)
#define LDAO 104   // ao [64][104] (attn out, 96 cols)
#define LDA  136   // A  [64][136] (LN1 out, then LN2 out)
#define LDH  136   // Hc [64][136] (MLP hidden chunk, double-buffered over QK/Vt)
#define OFF_VT  25600                 // 64*200*2
#define OFF_HC1 17408                 // 64*136*2
#define R1SZ    39424                 // OFF_VT + 96*72*2
#define OFF_AO  48640                 // R1SZ + 64*72*2
#define SMEMSZ  61952                 // OFF_AO + 64*104*2
__global__ __launch_bounds__(256, 2) void k_block(
    const float* __restrict__ pos, float* __restrict__ t,
    const float* __restrict__ g1, const float* __restrict__ b1,
    const unsigned short* __restrict__ Wqt,
    const unsigned short* __restrict__ Wot, const float* __restrict__ bo,
    const float* __restrict__ g2, const float* __restrict__ b2,
    const unsigned short* __restrict__ W1t, const float* __restrict__ bf1,
    const unsigned short* __restrict__ W2t, const float* __restrict__ bf2,
    int shifted)
{
    __shared__ __attribute__((aligned(16))) char smem[SMEMSZ];
    __shared__ float stats[64][4][2];
    __shared__ float ps[225];
    unsigned short* QK   = (unsigned short*)(smem);
    unsigned short* Vt   = (unsigned short*)(smem + OFF_VT);
    unsigned short* Hc0  = (unsigned short*)(smem);            // after attn done
    unsigned short* Hc1  = (unsigned short*)(smem + OFF_HC1);
    unsigned short* Abuf = (unsigned short*)(smem + R1SZ);     // LN1 out, later LN2 out
    unsigned short* P    = (unsigned short*)(smem + R1SZ);     // head loop (A1 dead)
    unsigned short* ao   = (unsigned short*)(smem + OFF_AO);

    int blk = blockIdx.x;              // 2048 = 8b x 256 windows
    int b   = blk >> 8;
    int win = blk & 255;
    int wy  = win >> 4, wx = win & 15;
    int tid = threadIdx.x, lane = tid & 63, w = tid >> 6;
    int lr  = lane & 15, lg = lane >> 4;
    int sh  = shifted ? 4 : 0;

    for (int idx = tid; idx < 225; idx += 256) ps[idx] = pos[idx];

    // ---- Phase 0: token indices + residual prefetch (t is read ONCE per block)
    int   toks[4][4];
    float t1raw[2][4][4];
    #pragma unroll
    for (int m = 0; m < 4; ++m)
        #pragma unroll
        for (int r = 0; r < 4; ++r) {
            int rowl = m*16 + lg*4 + r;
            int ir = rowl >> 3, ic = rowl & 7;
            int hh = (wy*8 + ir + sh) & 127, ww = (wx*8 + ic + sh) & 127;
            toks[m][r] = (b*128 + hh)*128 + ww;
            #pragma unroll
            for (int nt = 0; nt < 2; ++nt)
                t1raw[nt][m][r] = t[(size_t)toks[m][r]*128 + w*32 + nt*16 + lr];
        }
    float g1v[2], b1v[2];
    #pragma unroll
    for (int nt = 0; nt < 2; ++nt) {
        g1v[nt] = g1[w*32 + nt*16 + lr];
        b1v[nt] = b1[w*32 + nt*16 + lr];
    }

    // ---- Phase 1: LN1 from t1raw registers (LN2-style cross-wave stats)
    #pragma unroll
    for (int m = 0; m < 4; ++m)
        #pragma unroll
        for (int r = 0; r < 4; ++r) {
            float v0 = t1raw[0][m][r], v1 = t1raw[1][m][r];
            float s = v0 + v1, q = v0*v0 + v1*v1;
            #pragma unroll
            for (int o = 8; o; o >>= 1) { s += __shfl_xor(s, o); q += __shfl_xor(q, o); }
            if (lr == 0) {
                int rowl = m*16 + lg*4 + r;
                stats[rowl][w][0] = s;
                stats[rowl][w][1] = q;
            }
        }
    __syncthreads();
    #pragma unroll
    for (int m = 0; m < 4; ++m)
        #pragma unroll
        for (int r = 0; r < 4; ++r) {
            int rowl = m*16 + lg*4 + r;
            float s = 0.f, q = 0.f;
            #pragma unroll
            for (int ww2 = 0; ww2 < 4; ++ww2) { s += stats[rowl][ww2][0]; q += stats[rowl][ww2][1]; }
            float mean = s * 0.0078125f;
            float var  = fmaxf(q * 0.0078125f - mean*mean, 0.f);
            float rs   = rsqrtf(var + 1e-5f);
            #pragma unroll
            for (int nt = 0; nt < 2; ++nt) {
                int col = w*32 + nt*16 + lr;
                Abuf[rowl*LDA + col] = f2bf((t1raw[nt][m][r] - mean)*rs*g1v[nt] + b1v[nt]);
            }
        }
    // hoist first QKV B-tile frags: issued before the barrier, consumed right after
    frag8 bq0[4];
    #pragma unroll
    for (int ks = 0; ks < 4; ++ks)
        bq0[ks] = *reinterpret_cast<const frag8*>(Wqt + (size_t)(w*16 + lr)*128 + ks*32 + lg*8);
    __syncthreads();

    // ---- Phase 2: QKV GEMM (M=64, N=288, K=128): Q/K -> QK rows, V -> Vt transposed
    // compile-time unrolled tile loop (wave w owns tiles w, w+4, w+8, w+12[, w+16])
    __builtin_amdgcn_s_setprio(1);
    #pragma unroll
    for (int i = 0; i < 5; ++i) {
        if (i < 4 || w < 2) {
            int nt = w + i*4;
            f32x4 acc[4] = {};
            #pragma unroll
            for (int ks = 0; ks < 4; ++ks) {
                frag8 bfr = (i == 0) ? bq0[ks]
                    : *reinterpret_cast<const frag8*>(Wqt + (size_t)(nt*16 + lr)*128 + ks*32 + lg*8);
                #pragma unroll
                for (int m = 0; m < 4; ++m) {
                    frag8 af = *reinterpret_cast<const frag8*>(&Abuf[(m*16 + lr)*LDA + ks*32 + lg*8]);
                    acc[m] = __builtin_amdgcn_mfma_f32_16x16x32_bf16(af, bfr, acc[m], 0, 0, 0);
                }
            }
            if (nt < 12) {           // Q (pre-scaled in Wqt) and K
                #pragma unroll
                for (int m = 0; m < 4; ++m)
                    #pragma unroll
                    for (int r = 0; r < 4; ++r)
                        QK[(m*16 + lg*4 + r)*LDQK + nt*16 + lr] = f2bf(acc[m][r]);
            } else {                 // V transposed: Vt[d][token]
                #pragma unroll
                for (int m = 0; m < 4; ++m)
                    #pragma unroll
                    for (int r = 0; r < 4; ++r)
                        Vt[((nt - 12)*16 + lr)*LDVT + (m*16 + lg*4 + r)] = f2bf(acc[m][r]);
            }
        }
    }
    __builtin_amdgcn_s_setprio(0);
    __syncthreads();

    // ---- Phase 3: attention per head; wave w owns query rows w*16..w*16+15.
    bool mUL = (shifted != 0) && (wy == 15);
    bool mLR = (shifted != 0) && (wx == 15);
    #pragma unroll 1
    for (int h = 0; h < 3; ++h) {
        frag8 qf = *reinterpret_cast<const frag8*>(&QK[(w*16 + lr)*LDQK + h*32 + lg*8]);
        f32x4 s[4];
        #pragma unroll
        for (int jt = 0; jt < 4; ++jt) {
            frag8 kf = *reinterpret_cast<const frag8*>(&QK[(jt*16 + lr)*LDQK + 96 + h*32 + lg*8]);
            f32x4 z = {0.f, 0.f, 0.f, 0.f};
            s[jt] = __builtin_amdgcn_mfma_f32_16x16x32_bf16(qf, kf, z, 0, 0, 0);
        }
        #pragma unroll
        for (int r = 0; r < 4; ++r) {
            int i  = w*16 + lg*4 + r;
            int ir = i >> 3, ic = i & 7;
            int ro = (7 - ir)*15 + (7 - ic);
            float vals[4]; float mx = -1e30f;
            #pragma unroll
            for (int jt = 0; jt < 4; ++jt) {
                int j = jt*16 + lr, jr = j >> 3, jc = j & 7;
                float val = s[jt][r] + ps[ro + jr*15 + jc];
                if ((mUL && ((jr >= 4) != (ir >= 4))) || (mLR && ((jc >= 4) != (ic >= 4)))) val = -1e30f;
                vals[jt] = val; mx = fmaxf(mx, val);
            }
            #pragma unroll
            for (int o = 8; o; o >>= 1) mx = fmaxf(mx, __shfl_xor(mx, o));
            float sum = 0.f;
            #pragma unroll
            for (int jt = 0; jt < 4; ++jt) { vals[jt] = __expf(vals[jt] - mx); sum += vals[jt]; }
            #pragma unroll
            for (int o = 8; o; o >>= 1) sum += __shfl_xor(sum, o);
            float inv = __builtin_amdgcn_rcpf(sum);
            #pragma unroll
            for (int jt = 0; jt < 4; ++jt)
                P[i*LDP + jt*16 + lr] = f2bf(vals[jt] * inv);
        }
        #pragma unroll
        for (int nd = 0; nd < 2; ++nd) {
            f32x4 o4 = {0.f, 0.f, 0.f, 0.f};
            #pragma unroll
            for (int kt = 0; kt < 2; ++kt) {
                frag8 pf = *reinterpret_cast<const frag8*>(&P[(w*16 + lr)*LDP + kt*32 + lg*8]);
                frag8 vf = *reinterpret_cast<const frag8*>(&Vt[(h*32 + nd*16 + lr)*LDVT + kt*32 + lg*8]);
                o4 = __builtin_amdgcn_mfma_f32_16x16x32_bf16(pf, vf, o4, 0, 0, 0);
            }
            #pragma unroll
            for (int r = 0; r < 4; ++r)
                ao[(w*16 + lg*4 + r)*LDAO + h*32 + nd*16 + lr] = f2bf(o4[r]);
        }
    }
    // hoist proj B-frags before the ao barrier (in flight during attention tail)
    frag8 bwr[2][3];
    #pragma unroll
    for (int ks = 0; ks < 3; ++ks) {
        bwr[0][ks] = *reinterpret_cast<const frag8*>(Wot + (size_t)(w*32      + lr)*96 + ks*32 + lg*8);
        bwr[1][ks] = *reinterpret_cast<const frag8*>(Wot + (size_t)(w*32 + 16 + lr)*96 + ks*32 + lg*8);
    }
    __syncthreads();       // ao complete (cross-wave reads next)

    // ---- Phase 4: proj (96->128) + residual t1 in registers
    f32x4 pacc[2][4] = {};
    #pragma unroll
    for (int ks = 0; ks < 3; ++ks) {
        #pragma unroll
        for (int m = 0; m < 4; ++m) {
            frag8 af = *reinterpret_cast<const frag8*>(&ao[(m*16 + lr)*LDAO + ks*32 + lg*8]);
            pacc[0][m] = __builtin_amdgcn_mfma_f32_16x16x32_bf16(af, bwr[0][ks], pacc[0][m], 0, 0, 0);
            pacc[1][m] = __builtin_amdgcn_mfma_f32_16x16x32_bf16(af, bwr[1][ks], pacc[1][m], 0, 0, 0);
        }
    }
    float t1[2][4][4];
    #pragma unroll
    for (int nt = 0; nt < 2; ++nt) {
        float bov = bo[w*32 + nt*16 + lr];
        #pragma unroll
        for (int m = 0; m < 4; ++m)
            #pragma unroll
            for (int r = 0; r < 4; ++r)
                t1[nt][m][r] = t1raw[nt][m][r] + pacc[nt][m][r] + bov;
    }
    // ---- LN2 stats
    #pragma unroll
    for (int m = 0; m < 4; ++m)
        #pragma unroll
        for (int r = 0; r < 4; ++r) {
            float v0 = t1[0][m][r], v1 = t1[1][m][r];
            float s = v0 + v1, q = v0*v0 + v1*v1;
            #pragma unroll
            for (int o = 8; o; o >>= 1) { s += __shfl_xor(s, o); q += __shfl_xor(q, o); }
            if (lr == 0) {
                int rowl = m*16 + lg*4 + r;
                stats[rowl][w][0] = s;
                stats[rowl][w][1] = q;
            }
        }
    __syncthreads();       // stats ready; all proj reads of ao done -> A2 may overwrite
    #pragma unroll
    for (int m = 0; m < 4; ++m)
        #pragma unroll
        for (int r = 0; r < 4; ++r) {
            int rowl = m*16 + lg*4 + r;
            float s = 0.f, q = 0.f;
            #pragma unroll
            for (int ww2 = 0; ww2 < 4; ++ww2) { s += stats[rowl][ww2][0]; q += stats[rowl][ww2][1]; }
            float mean = s * 0.0078125f;
            float var  = fmaxf(q * 0.0078125f - mean*mean, 0.f);
            float rs   = rsqrtf(var + 1e-5f);
            #pragma unroll
            for (int nt = 0; nt < 2; ++nt) {
                int col = w*32 + nt*16 + lr;
                Abuf[rowl*LDA + col] = f2bf((t1[nt][m][r] - mean)*rs*g2[col] + b2[col]);
            }
        }
    // hoist W1 frags for chunk kc=0 before the A2 barrier
    frag8 w1f[2][4];
    #pragma unroll
    for (int nt = 0; nt < 2; ++nt)
        #pragma unroll
        for (int ks = 0; ks < 4; ++ks)
            w1f[nt][ks] = *reinterpret_cast<const frag8*>(
                W1t + (size_t)(w*32 + nt*16 + lr)*128 + ks*32 + lg*8);
    __syncthreads();       // A2 visible to all waves

    // ---- Phase 5: MLP, 4 hidden chunks of 128; weight loads software-pipelined
    f32x4 acc2[2][4] = {};
    #pragma unroll 1
    for (int kc = 0; kc < 4; ++kc) {
        unsigned short* Hc = (kc & 1) ? Hc1 : Hc0;
        f32x4 a1[2][4] = {};
        __builtin_amdgcn_s_setprio(1);
        #pragma unroll
        for (int ks = 0; ks < 4; ++ks) {
            frag8 af[4];
            #pragma unroll
            for (int m = 0; m < 4; ++m)
                af[m] = *reinterpret_cast<const frag8*>(&Abuf[(m*16 + lr)*LDA + ks*32 + lg*8]);
            #pragma unroll
            for (int nt = 0; nt < 2; ++nt) {
                #pragma unroll
                for (int m = 0; m < 4; ++m)
                    a1[nt][m] = __builtin_amdgcn_mfma_f32_16x16x32_bf16(af[m], w1f[nt][ks], a1[nt][m], 0, 0, 0);
            }
        }
        __builtin_amdgcn_s_setprio(0);
        // issue W2 frags for this chunk now (latency hides under gelu + barrier)
        frag8 w2f[2][4];
        #pragma unroll
        for (int nt = 0; nt < 2; ++nt)
            #pragma unroll
            for (int ks = 0; ks < 4; ++ks)
                w2f[nt][ks] = *reinterpret_cast<const frag8*>(
                    W2t + (size_t)(w*32 + nt*16 + lr)*512 + kc*128 + ks*32 + lg*8);
        #pragma unroll
        for (int nt = 0; nt < 2; ++nt)
            #pragma unroll
            for (int m = 0; m < 4; ++m)
                #pragma unroll
                for (int r = 0; r < 4; ++r) {
                    int rowl = m*16 + lg*4 + r;
                    int col  = w*32 + nt*16 + lr;
                    float xv = a1[nt][m][r] + bf1[kc*128 + col];
                    Hc[rowl*LDH + col] = f2bf(gelu_f(xv));
                }
        __syncthreads();   // Hc(kc) complete; prev buffer already consumed
        // issue W1 frags for next chunk (latency hides under GEMM2)
        if (kc < 3) {
            #pragma unroll
            for (int nt = 0; nt < 2; ++nt)
                #pragma unroll
                for (int ks = 0; ks < 4; ++ks)
                    w1f[nt][ks] = *reinterpret_cast<const frag8*>(
                        W1t + (size_t)((kc+1)*128 + w*32 + nt*16 + lr)*128 + ks*32 + lg*8);
        }
        __builtin_amdgcn_s_setprio(1);
        #pragma unroll
        for (int ks = 0; ks < 4; ++ks) {
            frag8 hfk[4];
            #pragma unroll
            for (int m = 0; m < 4; ++m)
                hfk[m] = *reinterpret_cast<const frag8*>(&Hc[(m*16 + lr)*LDH + ks*32 + lg*8]);
            #pragma unroll
            for (int nt = 0; nt < 2; ++nt) {
                #pragma unroll
                for (int m = 0; m < 4; ++m)
                    acc2[nt][m] = __builtin_amdgcn_mfma_f32_16x16x32_bf16(hfk[m], w2f[nt][ks], acc2[nt][m], 0, 0, 0);
            }
        }
        __builtin_amdgcn_s_setprio(0);
    }
    // ---- t2 = t1 + mlp + bf2 (scatter to source coords)
    #pragma unroll
    for (int nt = 0; nt < 2; ++nt) {
        float bfv = bf2[w*32 + nt*16 + lr];
        #pragma unroll
        for (int m = 0; m < 4; ++m)
            #pragma unroll
            for (int r = 0; r < 4; ++r)
                t[(size_t)toks[m][r]*128 + w*32 + nt*16 + lr] = t1[nt][m][r] + acc2[nt][m][r] + bfv;
    }
}

// ---------------------------------------------------------------- K7: NHWC -> NCHW transpose
__global__ __launch_bounds__(256) void k_transpose(
    const float* __restrict__ t, float* __restrict__ out)
{
    __shared__ float tile[128][33];
    int blk = blockIdx.x;                 // 8 * 128 * 4
    int ct = blk & 3;
    int h  = (blk >> 2) & 127;
    int b  = blk >> 9;
    const float* src = t + ((size_t)b*16384 + (size_t)h*128)*128 + ct*32;
    #pragma unroll
    for (int q = 0; q < 16; ++q) {
        int idx = threadIdx.x + q*256;
        int w = idx >> 5, c = idx & 31;
        tile[w][c] = src[(size_t)w*128 + c];
    }
    __syncthreads();
    float* dst = out + ((size_t)(b*128 + ct*32))*16384 + (size_t)h*128;
    #pragma unroll
    for (int q = 0; q < 16; ++q) {
        int idx = threadIdx.x + q*256;
        int c = idx >> 7, w = idx & 127;
        dst[(size_t)c*16384 + w] = tile[w][c];
    }
}

// ----------------------------------------------------------------
extern "C" void kernel_launch(void* const* d_in, const int* in_sizes, int n_in,
                              void* d_out, int out_size, void* d_ws, size_t ws_size,
                              hipStream_t stream)
{
    const float* x  = (const float*)d_in[0];
    const float* Wm = (const float*)d_in[1];
    const float* bm = (const float*)d_in[2];

    float* t           = (float*)d_ws;                 // T x 128 f32 (64 MB)
    unsigned short* wb = (unsigned short*)(t + (size_t)Timg*128);

    unsigned short* Wmt = wb;                    // [128][256]
    unsigned short* Wqt[2], *Wot[2], *W1t[2], *W2t[2];
    unsigned short* p = wb + 32768;
    for (int i = 0; i < 2; ++i) {
        Wqt[i] = p; p += 36864;   // [288][128]
        Wot[i] = p; p += 12288;   // [128][96]
        W1t[i] = p; p += 65536;   // [512][128]
        W2t[i] = p; p += 65536;   // [128][512]
    }

    // ---- one launch for all 9 weight converts
    WcvtAll wa;
    int slot = 0;
    auto put = [&](const float* s, unsigned short* d, int R, int C, int q) {
        wa.src[slot] = s; wa.dst[slot] = d; wa.R[slot] = R; wa.C[slot] = C; wa.qrows[slot] = q; ++slot;
    };
    put(Wm, Wmt, 256, 128, 0);
    for (int i = 0; i < 2; ++i) {
        put((const float*)d_in[ 5 + i*12], Wqt[i], 128, 288, 96);  // fold SCALE into Q cols
        put((const float*)d_in[ 7 + i*12], Wot[i],  96, 128, 0);
        put((const float*)d_in[11 + i*12], W1t[i], 128, 512, 0);
        put((const float*)d_in[13 + i*12], W2t[i], 512, 128, 0);
    }
    k_wcvt_all<<<dim3(256, 9), 256, 0, stream>>>(wa, SCALE);

    k_patchmerge<<<Timg/64, 256, 0, stream>>>(x, Wmt, bm, t);

    for (int blk = 0; blk < 2; ++blk) {
        const float* g1  = (const float*)d_in[ 3 + blk*12];
        const float* b1  = (const float*)d_in[ 4 + blk*12];
        const float* pos = (const float*)d_in[ 6 + blk*12];
        const float* bo  = (const float*)d_in[ 8 + blk*12];
        const float* g2  = (const float*)d_in[ 9 + blk*12];
        const float* b2  = (const float*)d_in[10 + blk*12];
        const float* bf1 = (const float*)d_in[12 + blk*12];
        const float* bf2 = (const float*)d_in[14 + blk*12];

        k_block<<<2048, 256, 0, stream>>>(pos, t, g1, b1, Wqt[blk],
                                          Wot[blk], bo, g2, b2,
                                          W1t[blk], bf1, W2t[blk], bf2, blk);
    }

    k_transpose<<<8*128*4, 256, 0, stream>>>(t, (float*)d_out);
}

// Round 18
// 343.522 us; speedup vs baseline: 1.0855x; 1.0855x over previous
//
#include <hip/hip_runtime.h>
#include <hip/hip_bf16.h>
#include <math.h>

#define Timg 131072            // 8 * 128 * 128 tokens after merge
#define SCALE 0.17677669529663689f

typedef __attribute__((ext_vector_type(8))) short frag8;
typedef __attribute__((ext_vector_type(4))) float f32x4;
typedef __attribute__((ext_vector_type(4))) unsigned int u32x4;

__device__ inline float bf2f(unsigned short u) {
    union { unsigned int i; float f; } v; v.i = ((unsigned int)u) << 16; return v.f;
}
// native cast -> compiler emits the hardware bf16 convert with full scheduling freedom
__device__ inline unsigned short f2bf(float f) {
    __hip_bfloat16 h = __float2bfloat16(f);
    return *reinterpret_cast<unsigned short*>(&h);
}
__device__ inline unsigned int pk2(float lo, float hi) {
    return ((unsigned int)f2bf(hi) << 16) | (unsigned int)f2bf(lo);
}
__device__ inline float gelu_f(float x) {
    float u = x * x;
    float z = x * fmaf(u, 0.044715f, 1.0f);                 // x + 0.044715 x^3
    float e = __builtin_amdgcn_exp2f(-2.3025851f * z);      // exp(-1.5957691*z)
    return x * __builtin_amdgcn_rcpf(1.f + e);
}

// ---------------------------------------------------------------- all weight converts in ONE launch
struct WcvtAll {
    const float* src[9];
    unsigned short* dst[9];
    int R[9];
    int C[9];
    int qrows[9];
};
__global__ __launch_bounds__(256) void k_wcvt_all(WcvtAll wa, float s)
{
    int wsel = blockIdx.y;
    int R = wa.R[wsel], C = wa.C[wsel];
    int idx = blockIdx.x * 256 + threadIdx.x;
    if (idx >= R * C) return;
    int r = idx / C, c = idx % C;
    float v = wa.src[wsel][idx];
    if (c < wa.qrows[wsel]) v *= s;
    wa.dst[wsel][(size_t)c * R + r] = f2bf(v);
}

// ---------------------------------------------------------------- K1: patch merge + MFMA GEMM (K=256 -> N=128), BM=64
#define LDA_PM 264
__global__ __launch_bounds__(256) void k_patchmerge(
    const float* __restrict__ x, const unsigned short* __restrict__ Wmt,
    const float* __restrict__ bm, float* __restrict__ t)
{
    __shared__ unsigned short A[64 * LDA_PM];
    int blk = blockIdx.x;              // 2048 = 8b x 128h x 2 halves
    int b   = blk >> 8;
    int rem = blk & 255;
    int h   = rem >> 1;
    int w0  = (rem & 1) * 64;
    int tid = threadIdx.x;
    {
        int row = tid >> 1, half = tid & 1;
        int c = row >> 1, ki = row & 1;
        const float* src = x + (((size_t)(b*64 + c))*256 + (size_t)(2*h + ki))*256 + 2*w0 + half*64;
        int base = c*4 + ki*2;
        #pragma unroll
        for (int q = 0; q < 16; ++q) {
            float4 v = *reinterpret_cast<const float4*>(src + q*4);
            int tk0 = (half*64 + q*4) >> 1;
            *reinterpret_cast<unsigned int*>(&A[ tk0     * LDA_PM + base]) = pk2(v.x, v.y);
            *reinterpret_cast<unsigned int*>(&A[(tk0 + 1)* LDA_PM + base]) = pk2(v.z, v.w);
        }
    }
    __syncthreads();
    int lane = tid & 63, w = tid >> 6;
    int lr = lane & 15, lg = lane >> 4;
    size_t tok0 = (size_t)blk * 64;
    #pragma unroll
    for (int nt = 0; nt < 2; ++nt) {
        int n0 = (w*2 + nt) * 16;
        f32x4 acc[4] = {};
        #pragma unroll
        for (int ks = 0; ks < 8; ++ks) {
            frag8 bfr = *reinterpret_cast<const frag8*>(Wmt + (size_t)(n0 + lr)*256 + ks*32 + lg*8);
            #pragma unroll
            for (int m = 0; m < 4; ++m) {
                frag8 af = *reinterpret_cast<const frag8*>(&A[(m*16 + lr)*LDA_PM + ks*32 + lg*8]);
                acc[m] = __builtin_amdgcn_mfma_f32_16x16x32_bf16(af, bfr, acc[m], 0, 0, 0);
            }
        }
        #pragma unroll
        for (int m = 0; m < 4; ++m)
            #pragma unroll
            for (int r = 0; r < 4; ++r) {
                int rowl = m*16 + lg*4 + r;
                int col  = n0 + lr;
                t[(tok0 + rowl)*128 + col] = acc[m][r] + bm[col];
            }
    }
}

// ---------------------------------------------------------------- K2: mega-kernel: one window (64 tokens) per block.
#define LDQK 200   // QK rows [64][200]: Q cols 0..95 (pre-scaled via Wq), K cols 96..191
#define LDVT 72    // Vt [96][72]  (V transposed: d-major)
#define LDP  72    // P  [64][72]  (softmax probs, wave-private rows)
#define LDAO 104   // ao [64][104] (attn out, 96 cols)
#define LDA  136   // A  [64][136] (LN1 out, then LN2 out)
#define LDH  136   // Hc [64][136] (MLP hidden chunk, double-buffered over QK/Vt)
#define OFF_VT  25600                 // 64*200*2
#define OFF_HC1 17408                 // 64*136*2
#define R1SZ    39424                 // OFF_VT + 96*72*2
#define OFF_AO  48640                 // R1SZ + 64*72*2
#define SMEMSZ  61952                 // OFF_AO + 64*104*2
__global__ __launch_bounds__(256, 2) void k_block(
    const float* __restrict__ pos, float* __restrict__ t,
    const float* __restrict__ g1, const float* __restrict__ b1,
    const unsigned short* __restrict__ Wqt,
    const unsigned short* __restrict__ Wot, const float* __restrict__ bo,
    const float* __restrict__ g2, const float* __restrict__ b2,
    const unsigned short* __restrict__ W1t, const float* __restrict__ bf1,
    const unsigned short* __restrict__ W2t, const float* __restrict__ bf2,
    int shifted)
{
    __shared__ __attribute__((aligned(16))) char smem[SMEMSZ];
    __shared__ float stats[64][4][2];
    unsigned short* QK   = (unsigned short*)(smem);
    unsigned short* Vt   = (unsigned short*)(smem + OFF_VT);
    unsigned short* Hc0  = (unsigned short*)(smem);            // after attn done
    unsigned short* Hc1  = (unsigned short*)(smem + OFF_HC1);
    unsigned short* Abuf = (unsigned short*)(smem + R1SZ);     // LN1 out, later LN2 out
    unsigned short* P    = (unsigned short*)(smem + R1SZ);     // head loop (A1 dead)
    unsigned short* ao   = (unsigned short*)(smem + OFF_AO);

    int blk = blockIdx.x;              // 2048 = 8b x 256 windows
    int b   = blk >> 8;
    int win = blk & 255;
    int wy  = win >> 4, wx = win & 15;
    int tid = threadIdx.x, lane = tid & 63, w = tid >> 6;
    int lr  = lane & 15, lg = lane >> 4;
    int l16 = lane & 15, quad = lane >> 4;
    int sh  = shifted ? 4 : 0;

    // ---- pos bias -> 16 registers (225-float table is L2-hot; removes the
    // per-iteration ps[] LDS gather from the softmax inner loop)
    float posb[4][4];
    #pragma unroll
    for (int r = 0; r < 4; ++r) {
        int i  = w*16 + lg*4 + r;
        int ir = i >> 3, ic = i & 7;
        #pragma unroll
        for (int jt = 0; jt < 4; ++jt) {
            int jr = (jt*16 + lr) >> 3, jc = lr & 7;
            posb[r][jt] = pos[(jr - ir + 7)*15 + (jc - ic + 7)];
        }
    }

    // ---- Phase 0: token indices + residual prefetch (T14 — latency hides under ph1-3)
    int   toks[4][4];
    float t1raw[2][4][4];
    #pragma unroll
    for (int m = 0; m < 4; ++m)
        #pragma unroll
        for (int r = 0; r < 4; ++r) {
            int rowl = m*16 + lg*4 + r;
            int ir = rowl >> 3, ic = rowl & 7;
            int hh = (wy*8 + ir + sh) & 127, ww = (wx*8 + ic + sh) & 127;
            toks[m][r] = (b*128 + hh)*128 + ww;
            #pragma unroll
            for (int nt = 0; nt < 2; ++nt)
                t1raw[nt][m][r] = t[(size_t)toks[m][r]*128 + w*32 + nt*16 + lr];
        }

    // ---- Phase 1: LN1, 16-lane groups, 4 rows in flight per wave
    float4 gv0 = *reinterpret_cast<const float4*>(g1 + l16*8);
    float4 gv1 = *reinterpret_cast<const float4*>(g1 + l16*8 + 4);
    float4 bv0 = *reinterpret_cast<const float4*>(b1 + l16*8);
    float4 bv1 = *reinterpret_cast<const float4*>(b1 + l16*8 + 4);
    #pragma unroll
    for (int it2 = 0; it2 < 4; ++it2) {
        int m  = w*16 + it2*4 + quad;
        int ir = m >> 3, ic = m & 7;
        int hh = (wy*8 + ir + sh) & 127, ww = (wx*8 + ic + sh) & 127;
        const float* p = t + ((size_t)((b*128 + hh)*128 + ww))*128 + l16*8;
        float4 v0 = *reinterpret_cast<const float4*>(p);
        float4 v1 = *reinterpret_cast<const float4*>(p + 4);
        float s = v0.x+v0.y+v0.z+v0.w + v1.x+v1.y+v1.z+v1.w;
        float q = v0.x*v0.x+v0.y*v0.y+v0.z*v0.z+v0.w*v0.w
                + v1.x*v1.x+v1.y*v1.y+v1.z*v1.z+v1.w*v1.w;
        #pragma unroll
        for (int o = 8; o; o >>= 1) { s += __shfl_xor(s, o); q += __shfl_xor(q, o); }
        float mean = s * 0.0078125f;
        float var  = fmaxf(q * 0.0078125f - mean*mean, 0.f);
        float rs   = rsqrtf(var + 1e-5f);
        u32x4 pk;
        pk.x = pk2((v0.x-mean)*rs*gv0.x + bv0.x, (v0.y-mean)*rs*gv0.y + bv0.y);
        pk.y = pk2((v0.z-mean)*rs*gv0.z + bv0.z, (v0.w-mean)*rs*gv0.w + bv0.w);
        pk.z = pk2((v1.x-mean)*rs*gv1.x + bv1.x, (v1.y-mean)*rs*gv1.y + bv1.y);
        pk.w = pk2((v1.z-mean)*rs*gv1.z + bv1.z, (v1.w-mean)*rs*gv1.w + bv1.w);
        *reinterpret_cast<u32x4*>(&Abuf[m*LDA + l16*8]) = pk;
    }
    // hoist first QKV B-tile frags: issued before the barrier, consumed right after
    frag8 bq0[4];
    #pragma unroll
    for (int ks = 0; ks < 4; ++ks)
        bq0[ks] = *reinterpret_cast<const frag8*>(Wqt + (size_t)(w*16 + lr)*128 + ks*32 + lg*8);
    __syncthreads();

    // ---- Phase 2: QKV GEMM (M=64, N=288, K=128): Q/K -> QK rows, V -> Vt transposed
    // compile-time unrolled tile loop (wave w owns tiles w, w+4, w+8, w+12[, w+16])
    __builtin_amdgcn_s_setprio(1);
    #pragma unroll
    for (int i = 0; i < 5; ++i) {
        if (i < 4 || w < 2) {
            int nt = w + i*4;
            f32x4 acc[4] = {};
            #pragma unroll
            for (int ks = 0; ks < 4; ++ks) {
                frag8 bfr = (i == 0) ? bq0[ks]
                    : *reinterpret_cast<const frag8*>(Wqt + (size_t)(nt*16 + lr)*128 + ks*32 + lg*8);
                #pragma unroll
                for (int m = 0; m < 4; ++m) {
                    frag8 af = *reinterpret_cast<const frag8*>(&Abuf[(m*16 + lr)*LDA + ks*32 + lg*8]);
                    acc[m] = __builtin_amdgcn_mfma_f32_16x16x32_bf16(af, bfr, acc[m], 0, 0, 0);
                }
            }
            if (nt < 12) {           // Q (pre-scaled in Wqt) and K
                #pragma unroll
                for (int m = 0; m < 4; ++m)
                    #pragma unroll
                    for (int r = 0; r < 4; ++r)
                        QK[(m*16 + lg*4 + r)*LDQK + nt*16 + lr] = f2bf(acc[m][r]);
            } else {                 // V transposed: Vt[d][token]
                #pragma unroll
                for (int m = 0; m < 4; ++m)
                    #pragma unroll
                    for (int r = 0; r < 4; ++r)
                        Vt[((nt - 12)*16 + lr)*LDVT + (m*16 + lg*4 + r)] = f2bf(acc[m][r]);
            }
        }
    }
    __builtin_amdgcn_s_setprio(0);
    __syncthreads();

    // ---- Phase 3: attention per head; wave w owns query rows w*16..w*16+15.
    bool mUL = (shifted != 0) && (wy == 15);
    bool mLR = (shifted != 0) && (wx == 15);
    #pragma unroll 1
    for (int h = 0; h < 3; ++h) {
        frag8 qf = *reinterpret_cast<const frag8*>(&QK[(w*16 + lr)*LDQK + h*32 + lg*8]);
        f32x4 s[4];
        #pragma unroll
        for (int jt = 0; jt < 4; ++jt) {
            frag8 kf = *reinterpret_cast<const frag8*>(&QK[(jt*16 + lr)*LDQK + 96 + h*32 + lg*8]);
            f32x4 z = {0.f, 0.f, 0.f, 0.f};
            s[jt] = __builtin_amdgcn_mfma_f32_16x16x32_bf16(qf, kf, z, 0, 0, 0);
        }
        #pragma unroll
        for (int r = 0; r < 4; ++r) {
            int i  = w*16 + lg*4 + r;
            int ir = i >> 3, ic = i & 7;
            float vals[4]; float mx = -1e30f;
            #pragma unroll
            for (int jt = 0; jt < 4; ++jt) {
                int j = jt*16 + lr, jr = j >> 3, jc = j & 7;
                float val = s[jt][r] + posb[r][jt];
                if ((mUL && ((jr >= 4) != (ir >= 4))) || (mLR && ((jc >= 4) != (ic >= 4)))) val = -1e30f;
                vals[jt] = val; mx = fmaxf(mx, val);
            }
            #pragma unroll
            for (int o = 8; o; o >>= 1) mx = fmaxf(mx, __shfl_xor(mx, o));
            float sum = 0.f;
            #pragma unroll
            for (int jt = 0; jt < 4; ++jt) { vals[jt] = __expf(vals[jt] - mx); sum += vals[jt]; }
            #pragma unroll
            for (int o = 8; o; o >>= 1) sum += __shfl_xor(sum, o);
            float inv = __builtin_amdgcn_rcpf(sum);
            #pragma unroll
            for (int jt = 0; jt < 4; ++jt)
                P[i*LDP + jt*16 + lr] = f2bf(vals[jt] * inv);
        }
        #pragma unroll
        for (int nd = 0; nd < 2; ++nd) {
            f32x4 o4 = {0.f, 0.f, 0.f, 0.f};
            #pragma unroll
            for (int kt = 0; kt < 2; ++kt) {
                frag8 pf = *reinterpret_cast<const frag8*>(&P[(w*16 + lr)*LDP + kt*32 + lg*8]);
                frag8 vf = *reinterpret_cast<const frag8*>(&Vt[(h*32 + nd*16 + lr)*LDVT + kt*32 + lg*8]);
                o4 = __builtin_amdgcn_mfma_f32_16x16x32_bf16(pf, vf, o4, 0, 0, 0);
            }
            #pragma unroll
            for (int r = 0; r < 4; ++r)
                ao[(w*16 + lg*4 + r)*LDAO + h*32 + nd*16 + lr] = f2bf(o4[r]);
        }
    }
    // hoist proj B-frags before the ao barrier (in flight during attention tail)
    frag8 bwr[2][3];
    #pragma unroll
    for (int ks = 0; ks < 3; ++ks) {
        bwr[0][ks] = *reinterpret_cast<const frag8*>(Wot + (size_t)(w*32      + lr)*96 + ks*32 + lg*8);
        bwr[1][ks] = *reinterpret_cast<const frag8*>(Wot + (size_t)(w*32 + 16 + lr)*96 + ks*32 + lg*8);
    }
    __syncthreads();       // ao complete (cross-wave reads next)

    // ---- Phase 4: proj (96->128) + residual t1 in registers
    f32x4 pacc[2][4] = {};
    #pragma unroll
    for (int ks = 0; ks < 3; ++ks) {
        #pragma unroll
        for (int m = 0; m < 4; ++m) {
            frag8 af = *reinterpret_cast<const frag8*>(&ao[(m*16 + lr)*LDAO + ks*32 + lg*8]);
            pacc[0][m] = __builtin_amdgcn_mfma_f32_16x16x32_bf16(af, bwr[0][ks], pacc[0][m], 0, 0, 0);
            pacc[1][m] = __builtin_amdgcn_mfma_f32_16x16x32_bf16(af, bwr[1][ks], pacc[1][m], 0, 0, 0);
        }
    }
    float t1[2][4][4];
    #pragma unroll
    for (int nt = 0; nt < 2; ++nt) {
        float bov = bo[w*32 + nt*16 + lr];
        #pragma unroll
        for (int m = 0; m < 4; ++m)
            #pragma unroll
            for (int r = 0; r < 4; ++r)
                t1[nt][m][r] = t1raw[nt][m][r] + pacc[nt][m][r] + bov;
    }
    // ---- LN2 stats
    #pragma unroll
    for (int m = 0; m < 4; ++m)
        #pragma unroll
        for (int r = 0; r < 4; ++r) {
            float v0 = t1[0][m][r], v1 = t1[1][m][r];
            float s = v0 + v1, q = v0*v0 + v1*v1;
            #pragma unroll
            for (int o = 8; o; o >>= 1) { s += __shfl_xor(s, o); q += __shfl_xor(q, o); }
            if (lr == 0) {
                int rowl = m*16 + lg*4 + r;
                stats[rowl][w][0] = s;
                stats[rowl][w][1] = q;
            }
        }
    __syncthreads();       // stats ready; all proj reads of ao done -> A2 may overwrite
    #pragma unroll
    for (int m = 0; m < 4; ++m)
        #pragma unroll
        for (int r = 0; r < 4; ++r) {
            int rowl = m*16 + lg*4 + r;
            float s = 0.f, q = 0.f;
            #pragma unroll
            for (int ww2 = 0; ww2 < 4; ++ww2) { s += stats[rowl][ww2][0]; q += stats[rowl][ww2][1]; }
            float mean = s * 0.0078125f;
            float var  = fmaxf(q * 0.0078125f - mean*mean, 0.f);
            float rs   = rsqrtf(var + 1e-5f);
            #pragma unroll
            for (int nt = 0; nt < 2; ++nt) {
                int col = w*32 + nt*16 + lr;
                Abuf[rowl*LDA + col] = f2bf((t1[nt][m][r] - mean)*rs*g2[col] + b2[col]);
            }
        }
    // hoist W1 frags for chunk kc=0 before the A2 barrier
    frag8 w1f[2][4];
    #pragma unroll
    for (int nt = 0; nt < 2; ++nt)
        #pragma unroll
        for (int ks = 0; ks < 4; ++ks)
            w1f[nt][ks] = *reinterpret_cast<const frag8*>(
                W1t + (size_t)(w*32 + nt*16 + lr)*128 + ks*32 + lg*8);
    __syncthreads();       // A2 visible to all waves

    // ---- Phase 5: MLP, 4 hidden chunks of 128; weight loads software-pipelined
    f32x4 acc2[2][4] = {};
    #pragma unroll 1
    for (int kc = 0; kc < 4; ++kc) {
        unsigned short* Hc = (kc & 1) ? Hc1 : Hc0;
        f32x4 a1[2][4] = {};
        __builtin_amdgcn_s_setprio(1);
        #pragma unroll
        for (int ks = 0; ks < 4; ++ks) {
            frag8 af[4];
            #pragma unroll
            for (int m = 0; m < 4; ++m)
                af[m] = *reinterpret_cast<const frag8*>(&Abuf[(m*16 + lr)*LDA + ks*32 + lg*8]);
            #pragma unroll
            for (int nt = 0; nt < 2; ++nt) {
                #pragma unroll
                for (int m = 0; m < 4; ++m)
                    a1[nt][m] = __builtin_amdgcn_mfma_f32_16x16x32_bf16(af[m], w1f[nt][ks], a1[nt][m], 0, 0, 0);
            }
        }
        __builtin_amdgcn_s_setprio(0);
        // issue W2 frags for this chunk now (latency hides under gelu + barrier)
        frag8 w2f[2][4];
        #pragma unroll
        for (int nt = 0; nt < 2; ++nt)
            #pragma unroll
            for (int ks = 0; ks < 4; ++ks)
                w2f[nt][ks] = *reinterpret_cast<const frag8*>(
                    W2t + (size_t)(w*32 + nt*16 + lr)*512 + kc*128 + ks*32 + lg*8);
        #pragma unroll
        for (int nt = 0; nt < 2; ++nt)
            #pragma unroll
            for (int m = 0; m < 4; ++m)
                #pragma unroll
                for (int r = 0; r < 4; ++r) {
                    int rowl = m*16 + lg*4 + r;
                    int col  = w*32 + nt*16 + lr;
                    float xv = a1[nt][m][r] + bf1[kc*128 + col];
                    Hc[rowl*LDH + col] = f2bf(gelu_f(xv));
                }
        __syncthreads();   // Hc(kc) complete; prev buffer already consumed
        // issue W1 frags for next chunk (latency hides under GEMM2)
        if (kc < 3) {
            #pragma unroll
            for (int nt = 0; nt < 2; ++nt)
                #pragma unroll
                for (int ks = 0; ks < 4; ++ks)
                    w1f[nt][ks] = *reinterpret_cast<const frag8*>(
                        W1t + (size_t)((kc+1)*128 + w*32 + nt*16 + lr)*128 + ks*32 + lg*8);
        }
        __builtin_amdgcn_s_setprio(1);
        #pragma unroll
        for (int ks = 0; ks < 4; ++ks) {
            frag8 hfk[4];
            #pragma unroll
            for (int m = 0; m < 4; ++m)
                hfk[m] = *reinterpret_cast<const frag8*>(&Hc[(m*16 + lr)*LDH + ks*32 + lg*8]);
            #pragma unroll
            for (int nt = 0; nt < 2; ++nt) {
                #pragma unroll
                for (int m = 0; m < 4; ++m)
                    acc2[nt][m] = __builtin_amdgcn_mfma_f32_16x16x32_bf16(hfk[m], w2f[nt][ks], acc2[nt][m], 0, 0, 0);
            }
        }
        __builtin_amdgcn_s_setprio(0);
    }
    // ---- t2 = t1 + mlp + bf2 (scatter to source coords)
    #pragma unroll
    for (int nt = 0; nt < 2; ++nt) {
        float bfv = bf2[w*32 + nt*16 + lr];
        #pragma unroll
        for (int m = 0; m < 4; ++m)
            #pragma unroll
            for (int r = 0; r < 4; ++r)
                t[(size_t)toks[m][r]*128 + w*32 + nt*16 + lr] = t1[nt][m][r] + acc2[nt][m][r] + bfv;
    }
}

// ---------------------------------------------------------------- K7: NHWC -> NCHW transpose
__global__ __launch_bounds__(256) void k_transpose(
    const float* __restrict__ t, float* __restrict__ out)
{
    __shared__ float tile[128][33];
    int blk = blockIdx.x;                 // 8 * 128 * 4
    int ct = blk & 3;
    int h  = (blk >> 2) & 127;
    int b  = blk >> 9;
    const float* src = t + ((size_t)b*16384 + (size_t)h*128)*128 + ct*32;
    #pragma unroll
    for (int q = 0; q < 16; ++q) {
        int idx = threadIdx.x + q*256;
        int w = idx >> 5, c = idx & 31;
        tile[w][c] = src[(size_t)w*128 + c];
    }
    __syncthreads();
    float* dst = out + ((size_t)(b*128 + ct*32))*16384 + (size_t)h*128;
    #pragma unroll
    for (int q = 0; q < 16; ++q) {
        int idx = threadIdx.x + q*256;
        int c = idx >> 7, w = idx & 127;
        dst[(size_t)c*16384 + w] = tile[w][c];
    }
}

// ----------------------------------------------------------------
extern "C" void kernel_launch(void* const* d_in, const int* in_sizes, int n_in,
                              void* d_out, int out_size, void* d_ws, size_t ws_size,
                              hipStream_t stream)
{
    const float* x  = (const float*)d_in[0];
    const float* Wm = (const float*)d_in[1];
    const float* bm = (const float*)d_in[2];

    float* t           = (float*)d_ws;                 // T x 128 f32 (64 MB)
    unsigned short* wb = (unsigned short*)(t + (size_t)Timg*128);

    unsigned short* Wmt = wb;                    // [128][256]
    unsigned short* Wqt[2], *Wot[2], *W1t[2], *W2t[2];
    unsigned short* p = wb + 32768;
    for (int i = 0; i < 2; ++i) {
        Wqt[i] = p; p += 36864;   // [288][128]
        Wot[i] = p; p += 12288;   // [128][96]
        W1t[i] = p; p += 65536;   // [512][128]
        W2t[i] = p; p += 65536;   // [128][512]
    }

    // ---- one launch for all 9 weight converts
    WcvtAll wa;
    int slot = 0;
    auto put = [&](const float* s, unsigned short* d, int R, int C, int q) {
        wa.src[slot] = s; wa.dst[slot] = d; wa.R[slot] = R; wa.C[slot] = C; wa.qrows[slot] = q; ++slot;
    };
    put(Wm, Wmt, 256, 128, 0);
    for (int i = 0; i < 2; ++i) {
        put((const float*)d_in[ 5 + i*12], Wqt[i], 128, 288, 96);  // fold SCALE into Q cols
        put((const float*)d_in[ 7 + i*12], Wot[i],  96, 128, 0);
        put((const float*)d_in[11 + i*12], W1t[i], 128, 512, 0);
        put((const float*)d_in[13 + i*12], W2t[i], 512, 128, 0);
    }
    k_wcvt_all<<<dim3(256, 9), 256, 0, stream>>>(wa, SCALE);

    k_patchmerge<<<Timg/64, 256, 0, stream>>>(x, Wmt, bm, t);

    for (int blk = 0; blk < 2; ++blk) {
        const float* g1  = (const float*)d_in[ 3 + blk*12];
        const float* b1  = (const float*)d_in[ 4 + blk*12];
        const float* pos = (const float*)d_in[ 6 + blk*12];
        const float* bo  = (const float*)d_in[ 8 + blk*12];
        const float* g2  = (const float*)d_in[ 9 + blk*12];
        const float* b2  = (const float*)d_in[10 + blk*12];
        const float* bf1 = (const float*)d_in[12 + blk*12];
        const float* bf2 = (const float*)d_in[14 + blk*12];

        k_block<<<2048, 256, 0, stream>>>(pos, t, g1, b1, Wqt[blk],
                                          Wot[blk], bo, g2, b2,
                                          W1t[blk], bf1, W2t[blk], bf2, blk);
    }

    k_transpose<<<8*128*4, 256, 0, stream>>>(t, (float*)d_out);
}

// Round 19
// 340.427 us; speedup vs baseline: 1.0954x; 1.0091x over previous
//
#include <hip/hip_runtime.h>
#include <hip/hip_bf16.h>
#include <math.h>

#define Timg 131072            // 8 * 128 * 128 tokens after merge
#define SCALE 0.17677669529663689f

typedef __attribute__((ext_vector_type(8))) short frag8;
typedef __attribute__((ext_vector_type(4))) float f32x4;
typedef __attribute__((ext_vector_type(4))) unsigned int u32x4;

__device__ inline float bf2f(unsigned short u) {
    union { unsigned int i; float f; } v; v.i = ((unsigned int)u) << 16; return v.f;
}
// native cast -> compiler emits the hardware bf16 convert with full scheduling freedom
__device__ inline unsigned short f2bf(float f) {
    __hip_bfloat16 h = __float2bfloat16(f);
    return *reinterpret_cast<unsigned short*>(&h);
}
__device__ inline unsigned int pk2(float lo, float hi) {
    return ((unsigned int)f2bf(hi) << 16) | (unsigned int)f2bf(lo);
}
__device__ inline float gelu_f(float x) {
    float u = x * x;
    float z = x * fmaf(u, 0.044715f, 1.0f);                 // x + 0.044715 x^3
    float e = __builtin_amdgcn_exp2f(-2.3025851f * z);      // exp(-1.5957691*z)
    return x * __builtin_amdgcn_rcpf(1.f + e);
}

// ---------------------------------------------------------------- all weight converts in ONE launch
struct WcvtAll {
    const float* src[9];
    unsigned short* dst[9];
    int R[9];
    int C[9];
    int qrows[9];
};
__global__ __launch_bounds__(256) void k_wcvt_all(WcvtAll wa, float s)
{
    int wsel = blockIdx.y;
    int R = wa.R[wsel], C = wa.C[wsel];
    int idx = blockIdx.x * 256 + threadIdx.x;
    if (idx >= R * C) return;
    int r = idx / C, c = idx % C;
    float v = wa.src[wsel][idx];
    if (c < wa.qrows[wsel]) v *= s;
    wa.dst[wsel][(size_t)c * R + r] = f2bf(v);
}

// ---------------------------------------------------------------- K1: patch merge + MFMA GEMM (K=256 -> N=128), BM=64
#define LDA_PM 264
__global__ __launch_bounds__(256) void k_patchmerge(
    const float* __restrict__ x, const unsigned short* __restrict__ Wmt,
    const float* __restrict__ bm, float* __restrict__ t)
{
    __shared__ unsigned short A[64 * LDA_PM];
    int blk = blockIdx.x;              // 2048 = 8b x 128h x 2 halves
    int b   = blk >> 8;
    int rem = blk & 255;
    int h   = rem >> 1;
    int w0  = (rem & 1) * 64;
    int tid = threadIdx.x;
    {
        int row = tid >> 1, half = tid & 1;
        int c = row >> 1, ki = row & 1;
        const float* src = x + (((size_t)(b*64 + c))*256 + (size_t)(2*h + ki))*256 + 2*w0 + half*64;
        int base = c*4 + ki*2;
        #pragma unroll
        for (int q = 0; q < 16; ++q) {
            float4 v = *reinterpret_cast<const float4*>(src + q*4);
            int tk0 = (half*64 + q*4) >> 1;
            *reinterpret_cast<unsigned int*>(&A[ tk0     * LDA_PM + base]) = pk2(v.x, v.y);
            *reinterpret_cast<unsigned int*>(&A[(tk0 + 1)* LDA_PM + base]) = pk2(v.z, v.w);
        }
    }
    __syncthreads();
    int lane = tid & 63, w = tid >> 6;
    int lr = lane & 15, lg = lane >> 4;
    size_t tok0 = (size_t)blk * 64;
    #pragma unroll
    for (int nt = 0; nt < 2; ++nt) {
        int n0 = (w*2 + nt) * 16;
        f32x4 acc[4] = {};
        #pragma unroll
        for (int ks = 0; ks < 8; ++ks) {
            frag8 bfr = *reinterpret_cast<const frag8*>(Wmt + (size_t)(n0 + lr)*256 + ks*32 + lg*8);
            #pragma unroll
            for (int m = 0; m < 4; ++m) {
                frag8 af = *reinterpret_cast<const frag8*>(&A[(m*16 + lr)*LDA_PM + ks*32 + lg*8]);
                acc[m] = __builtin_amdgcn_mfma_f32_16x16x32_bf16(af, bfr, acc[m], 0, 0, 0);
            }
        }
        #pragma unroll
        for (int m = 0; m < 4; ++m)
            #pragma unroll
            for (int r = 0; r < 4; ++r) {
                int rowl = m*16 + lg*4 + r;
                int col  = n0 + lr;
                t[(tok0 + rowl)*128 + col] = acc[m][r] + bm[col];
            }
    }
}

// ---------------------------------------------------------------- K2: mega-kernel: one window (64 tokens) per block.
#define LDQK 200   // QK rows [64][200]: Q cols 0..95 (pre-scaled via Wq), K cols 96..191
#define LDVT 72    // Vt [96][72]  (V transposed: d-major)
#define LDP  72    // P  [64][72]  (softmax probs, wave-private rows)
#define LDAO 104   // ao [64][104] (attn out, 96 cols)
#define LDA  136   // A  [64][136] (LN1 out, then LN2 out)
#define LDH  136   // Hc [64][136] (MLP hidden chunk, double-buffered over QK/Vt)
#define OFF_VT  25600                 // 64*200*2
#define OFF_HC1 17408                 // 64*136*2
#define R1SZ    39424                 // OFF_VT + 96*72*2
#define OFF_AO  48640                 // R1SZ + 64*72*2
#define SMEMSZ  61952                 // OFF_AO + 64*104*2
__global__ __launch_bounds__(256, 2) void k_block(
    const float* __restrict__ pos, float* __restrict__ t,
    const float* __restrict__ g1, const float* __restrict__ b1,
    const unsigned short* __restrict__ Wqt,
    const unsigned short* __restrict__ Wot, const float* __restrict__ bo,
    const float* __restrict__ g2, const float* __restrict__ b2,
    const unsigned short* __restrict__ W1t, const float* __restrict__ bf1,
    const unsigned short* __restrict__ W2t, const float* __restrict__ bf2,
    int shifted)
{
    __shared__ __attribute__((aligned(16))) char smem[SMEMSZ];
    __shared__ float stats[64][4][2];
    unsigned short* QK   = (unsigned short*)(smem);
    unsigned short* Vt   = (unsigned short*)(smem + OFF_VT);
    unsigned short* Hc0  = (unsigned short*)(smem);            // after attn done
    unsigned short* Hc1  = (unsigned short*)(smem + OFF_HC1);
    unsigned short* Abuf = (unsigned short*)(smem + R1SZ);     // LN1 out, later LN2 out
    unsigned short* P    = (unsigned short*)(smem + R1SZ);     // head loop (A1 dead)
    unsigned short* ao   = (unsigned short*)(smem + OFF_AO);

    int blk = blockIdx.x;              // 2048 = 8b x 256 windows
    int b   = blk >> 8;
    int win = blk & 255;
    int wy  = win >> 4, wx = win & 15;
    int tid = threadIdx.x, lane = tid & 63, w = tid >> 6;
    int lr  = lane & 15, lg = lane >> 4;
    int l16 = lane & 15, quad = lane >> 4;
    int sh  = shifted ? 4 : 0;

    // ---- pos bias -> 16 registers (225-float table is L2-hot)
    float posb[4][4];
    #pragma unroll
    for (int r = 0; r < 4; ++r) {
        int i  = w*16 + lg*4 + r;
        int ir = i >> 3, ic = i & 7;
        #pragma unroll
        for (int jt = 0; jt < 4; ++jt) {
            int jr = (jt*16 + lr) >> 3, jc = lr & 7;
            posb[r][jt] = pos[(jr - ir + 7)*15 + (jc - ic + 7)];
        }
    }

    // ---- Phase 0: token indices + residual prefetch (T14 — latency hides under ph1-3)
    int   toks[4][4];
    float t1raw[2][4][4];
    #pragma unroll
    for (int m = 0; m < 4; ++m)
        #pragma unroll
        for (int r = 0; r < 4; ++r) {
            int rowl = m*16 + lg*4 + r;
            int ir = rowl >> 3, ic = rowl & 7;
            int hh = (wy*8 + ir + sh) & 127, ww = (wx*8 + ic + sh) & 127;
            toks[m][r] = (b*128 + hh)*128 + ww;
            #pragma unroll
            for (int nt = 0; nt < 2; ++nt)
                t1raw[nt][m][r] = t[(size_t)toks[m][r]*128 + w*32 + nt*16 + lr];
        }

    // ---- Phase 1: LN1, 16-lane groups, 4 rows in flight per wave
    float4 gv0 = *reinterpret_cast<const float4*>(g1 + l16*8);
    float4 gv1 = *reinterpret_cast<const float4*>(g1 + l16*8 + 4);
    float4 bv0 = *reinterpret_cast<const float4*>(b1 + l16*8);
    float4 bv1 = *reinterpret_cast<const float4*>(b1 + l16*8 + 4);
    #pragma unroll
    for (int it2 = 0; it2 < 4; ++it2) {
        int m  = w*16 + it2*4 + quad;
        int ir = m >> 3, ic = m & 7;
        int hh = (wy*8 + ir + sh) & 127, ww = (wx*8 + ic + sh) & 127;
        const float* p = t + ((size_t)((b*128 + hh)*128 + ww))*128 + l16*8;
        float4 v0 = *reinterpret_cast<const float4*>(p);
        float4 v1 = *reinterpret_cast<const float4*>(p + 4);
        float s = v0.x+v0.y+v0.z+v0.w + v1.x+v1.y+v1.z+v1.w;
        float q = v0.x*v0.x+v0.y*v0.y+v0.z*v0.z+v0.w*v0.w
                + v1.x*v1.x+v1.y*v1.y+v1.z*v1.z+v1.w*v1.w;
        #pragma unroll
        for (int o = 8; o; o >>= 1) { s += __shfl_xor(s, o); q += __shfl_xor(q, o); }
        float mean = s * 0.0078125f;
        float var  = fmaxf(q * 0.0078125f - mean*mean, 0.f);
        float rs   = rsqrtf(var + 1e-5f);
        u32x4 pk;
        pk.x = pk2((v0.x-mean)*rs*gv0.x + bv0.x, (v0.y-mean)*rs*gv0.y + bv0.y);
        pk.y = pk2((v0.z-mean)*rs*gv0.z + bv0.z, (v0.w-mean)*rs*gv0.w + bv0.w);
        pk.z = pk2((v1.x-mean)*rs*gv1.x + bv1.x, (v1.y-mean)*rs*gv1.y + bv1.y);
        pk.w = pk2((v1.z-mean)*rs*gv1.z + bv1.z, (v1.w-mean)*rs*gv1.w + bv1.w);
        *reinterpret_cast<u32x4*>(&Abuf[m*LDA + l16*8]) = pk;
    }
    // hoist first QKV B-tile frags: issued before the barrier, consumed right after
    frag8 bq0[4];
    #pragma unroll
    for (int ks = 0; ks < 4; ++ks)
        bq0[ks] = *reinterpret_cast<const frag8*>(Wqt + (size_t)(w*16 + lr)*128 + ks*32 + lg*8);
    __syncthreads();

    // ---- Phase 2: QKV GEMM (M=64, N=288, K=128): Q/K -> QK rows, V -> Vt transposed
    __builtin_amdgcn_s_setprio(1);
    #pragma unroll
    for (int i = 0; i < 5; ++i) {
        if (i < 4 || w < 2) {
            int nt = w + i*4;
            f32x4 acc[4] = {};
            #pragma unroll
            for (int ks = 0; ks < 4; ++ks) {
                frag8 bfr = (i == 0) ? bq0[ks]
                    : *reinterpret_cast<const frag8*>(Wqt + (size_t)(nt*16 + lr)*128 + ks*32 + lg*8);
                #pragma unroll
                for (int m = 0; m < 4; ++m) {
                    frag8 af = *reinterpret_cast<const frag8*>(&Abuf[(m*16 + lr)*LDA + ks*32 + lg*8]);
                    acc[m] = __builtin_amdgcn_mfma_f32_16x16x32_bf16(af, bfr, acc[m], 0, 0, 0);
                }
            }
            if (nt < 12) {           // Q (pre-scaled in Wqt) and K
                #pragma unroll
                for (int m = 0; m < 4; ++m)
                    #pragma unroll
                    for (int r = 0; r < 4; ++r)
                        QK[(m*16 + lg*4 + r)*LDQK + nt*16 + lr] = f2bf(acc[m][r]);
            } else {                 // V transposed: Vt[d][token]
                #pragma unroll
                for (int m = 0; m < 4; ++m)
                    #pragma unroll
                    for (int r = 0; r < 4; ++r)
                        Vt[((nt - 12)*16 + lr)*LDVT + (m*16 + lg*4 + r)] = f2bf(acc[m][r]);
            }
        }
    }
    __builtin_amdgcn_s_setprio(0);
    __syncthreads();

    // ---- Phase 3: attention, software-pipelined across heads:
    // QK^T(h+1) MFMAs issue between P(h)-write and P(h)-read (PV), hiding the
    // P LDS round-trip and overlapping softmax VALU with matrix-pipe work.
    bool mUL = (shifted != 0) && (wy == 15);
    bool mLR = (shifted != 0) && (wx == 15);
    f32x4 sA[4];
    {
        frag8 qf = *reinterpret_cast<const frag8*>(&QK[(w*16 + lr)*LDQK + 0*32 + lg*8]);
        #pragma unroll
        for (int jt = 0; jt < 4; ++jt) {
            frag8 kf = *reinterpret_cast<const frag8*>(&QK[(jt*16 + lr)*LDQK + 96 + 0*32 + lg*8]);
            f32x4 z = {0.f, 0.f, 0.f, 0.f};
            sA[jt] = __builtin_amdgcn_mfma_f32_16x16x32_bf16(qf, kf, z, 0, 0, 0);
        }
    }
    #pragma unroll
    for (int h = 0; h < 3; ++h) {
        // softmax on sA -> write P(h)
        #pragma unroll
        for (int r = 0; r < 4; ++r) {
            int i  = w*16 + lg*4 + r;
            int ir = i >> 3, ic = i & 7;
            float vals[4]; float mx = -1e30f;
            #pragma unroll
            for (int jt = 0; jt < 4; ++jt) {
                int j = jt*16 + lr, jr = j >> 3, jc = j & 7;
                float val = sA[jt][r] + posb[r][jt];
                if ((mUL && ((jr >= 4) != (ir >= 4))) || (mLR && ((jc >= 4) != (ic >= 4)))) val = -1e30f;
                vals[jt] = val; mx = fmaxf(mx, val);
            }
            #pragma unroll
            for (int o = 8; o; o >>= 1) mx = fmaxf(mx, __shfl_xor(mx, o));
            float sum = 0.f;
            #pragma unroll
            for (int jt = 0; jt < 4; ++jt) { vals[jt] = __expf(vals[jt] - mx); sum += vals[jt]; }
            #pragma unroll
            for (int o = 8; o; o >>= 1) sum += __shfl_xor(sum, o);
            float inv = __builtin_amdgcn_rcpf(sum);
            #pragma unroll
            for (int jt = 0; jt < 4; ++jt)
                P[i*LDP + jt*16 + lr] = f2bf(vals[jt] * inv);
        }
        // prefetch next head's scores (independent of P) — fills the P round-trip gap
        f32x4 sB[4];
        if (h < 2) {
            frag8 qfn = *reinterpret_cast<const frag8*>(&QK[(w*16 + lr)*LDQK + (h+1)*32 + lg*8]);
            #pragma unroll
            for (int jt = 0; jt < 4; ++jt) {
                frag8 kf = *reinterpret_cast<const frag8*>(&QK[(jt*16 + lr)*LDQK + 96 + (h+1)*32 + lg*8]);
                f32x4 z = {0.f, 0.f, 0.f, 0.f};
                sB[jt] = __builtin_amdgcn_mfma_f32_16x16x32_bf16(qfn, kf, z, 0, 0, 0);
            }
        }
        // PV for head h
        #pragma unroll
        for (int nd = 0; nd < 2; ++nd) {
            f32x4 o4 = {0.f, 0.f, 0.f, 0.f};
            #pragma unroll
            for (int kt = 0; kt < 2; ++kt) {
                frag8 pf = *reinterpret_cast<const frag8*>(&P[(w*16 + lr)*LDP + kt*32 + lg*8]);
                frag8 vf = *reinterpret_cast<const frag8*>(&Vt[(h*32 + nd*16 + lr)*LDVT + kt*32 + lg*8]);
                o4 = __builtin_amdgcn_mfma_f32_16x16x32_bf16(pf, vf, o4, 0, 0, 0);
            }
            #pragma unroll
            for (int r = 0; r < 4; ++r)
                ao[(w*16 + lg*4 + r)*LDAO + h*32 + nd*16 + lr] = f2bf(o4[r]);
        }
        if (h < 2) {
            #pragma unroll
            for (int jt = 0; jt < 4; ++jt) sA[jt] = sB[jt];
        }
    }
    // hoist proj B-frags before the ao barrier (in flight during attention tail)
    frag8 bwr[2][3];
    #pragma unroll
    for (int ks = 0; ks < 3; ++ks) {
        bwr[0][ks] = *reinterpret_cast<const frag8*>(Wot + (size_t)(w*32      + lr)*96 + ks*32 + lg*8);
        bwr[1][ks] = *reinterpret_cast<const frag8*>(Wot + (size_t)(w*32 + 16 + lr)*96 + ks*32 + lg*8);
    }
    __syncthreads();       // ao complete (cross-wave reads next)

    // ---- Phase 4: proj (96->128) + residual t1 in registers
    f32x4 pacc[2][4] = {};
    #pragma unroll
    for (int ks = 0; ks < 3; ++ks) {
        #pragma unroll
        for (int m = 0; m < 4; ++m) {
            frag8 af = *reinterpret_cast<const frag8*>(&ao[(m*16 + lr)*LDAO + ks*32 + lg*8]);
            pacc[0][m] = __builtin_amdgcn_mfma_f32_16x16x32_bf16(af, bwr[0][ks], pacc[0][m], 0, 0, 0);
            pacc[1][m] = __builtin_amdgcn_mfma_f32_16x16x32_bf16(af, bwr[1][ks], pacc[1][m], 0, 0, 0);
        }
    }
    float t1[2][4][4];
    #pragma unroll
    for (int nt = 0; nt < 2; ++nt) {
        float bov = bo[w*32 + nt*16 + lr];
        #pragma unroll
        for (int m = 0; m < 4; ++m)
            #pragma unroll
            for (int r = 0; r < 4; ++r)
                t1[nt][m][r] = t1raw[nt][m][r] + pacc[nt][m][r] + bov;
    }
    // ---- LN2 stats
    #pragma unroll
    for (int m = 0; m < 4; ++m)
        #pragma unroll
        for (int r = 0; r < 4; ++r) {
            float v0 = t1[0][m][r], v1 = t1[1][m][r];
            float s = v0 + v1, q = v0*v0 + v1*v1;
            #pragma unroll
            for (int o = 8; o; o >>= 1) { s += __shfl_xor(s, o); q += __shfl_xor(q, o); }
            if (lr == 0) {
                int rowl = m*16 + lg*4 + r;
                stats[rowl][w][0] = s;
                stats[rowl][w][1] = q;
            }
        }
    __syncthreads();       // stats ready; all proj reads of ao done -> A2 may overwrite
    #pragma unroll
    for (int m = 0; m < 4; ++m)
        #pragma unroll
        for (int r = 0; r < 4; ++r) {
            int rowl = m*16 + lg*4 + r;
            float s = 0.f, q = 0.f;
            #pragma unroll
            for (int ww2 = 0; ww2 < 4; ++ww2) { s += stats[rowl][ww2][0]; q += stats[rowl][ww2][1]; }
            float mean = s * 0.0078125f;
            float var  = fmaxf(q * 0.0078125f - mean*mean, 0.f);
            float rs   = rsqrtf(var + 1e-5f);
            #pragma unroll
            for (int nt = 0; nt < 2; ++nt) {
                int col = w*32 + nt*16 + lr;
                Abuf[rowl*LDA + col] = f2bf((t1[nt][m][r] - mean)*rs*g2[col] + b2[col]);
            }
        }
    // hoist W1 frags for chunk kc=0 before the A2 barrier
    frag8 w1f[2][4];
    #pragma unroll
    for (int nt = 0; nt < 2; ++nt)
        #pragma unroll
        for (int ks = 0; ks < 4; ++ks)
            w1f[nt][ks] = *reinterpret_cast<const frag8*>(
                W1t + (size_t)(w*32 + nt*16 + lr)*128 + ks*32 + lg*8);
    __syncthreads();       // A2 visible to all waves

    // ---- Phase 5: MLP, 4 hidden chunks of 128; weight loads software-pipelined
    f32x4 acc2[2][4] = {};
    #pragma unroll 1
    for (int kc = 0; kc < 4; ++kc) {
        unsigned short* Hc = (kc & 1) ? Hc1 : Hc0;
        f32x4 a1[2][4] = {};
        __builtin_amdgcn_s_setprio(1);
        #pragma unroll
        for (int ks = 0; ks < 4; ++ks) {
            frag8 af[4];
            #pragma unroll
            for (int m = 0; m < 4; ++m)
                af[m] = *reinterpret_cast<const frag8*>(&Abuf[(m*16 + lr)*LDA + ks*32 + lg*8]);
            #pragma unroll
            for (int nt = 0; nt < 2; ++nt) {
                #pragma unroll
                for (int m = 0; m < 4; ++m)
                    a1[nt][m] = __builtin_amdgcn_mfma_f32_16x16x32_bf16(af[m], w1f[nt][ks], a1[nt][m], 0, 0, 0);
            }
        }
        __builtin_amdgcn_s_setprio(0);
        // issue W2 frags for this chunk now (latency hides under gelu + barrier)
        frag8 w2f[2][4];
        #pragma unroll
        for (int nt = 0; nt < 2; ++nt)
            #pragma unroll
            for (int ks = 0; ks < 4; ++ks)
                w2f[nt][ks] = *reinterpret_cast<const frag8*>(
                    W2t + (size_t)(w*32 + nt*16 + lr)*512 + kc*128 + ks*32 + lg*8);
        #pragma unroll
        for (int nt = 0; nt < 2; ++nt)
            #pragma unroll
            for (int m = 0; m < 4; ++m)
                #pragma unroll
                for (int r = 0; r < 4; ++r) {
                    int rowl = m*16 + lg*4 + r;
                    int col  = w*32 + nt*16 + lr;
                    float xv = a1[nt][m][r] + bf1[kc*128 + col];
                    Hc[rowl*LDH + col] = f2bf(gelu_f(xv));
                }
        __syncthreads();   // Hc(kc) complete; prev buffer already consumed
        // issue W1 frags for next chunk (latency hides under GEMM2)
        if (kc < 3) {
            #pragma unroll
            for (int nt = 0; nt < 2; ++nt)
                #pragma unroll
                for (int ks = 0; ks < 4; ++ks)
                    w1f[nt][ks] = *reinterpret_cast<const frag8*>(
                        W1t + (size_t)((kc+1)*128 + w*32 + nt*16 + lr)*128 + ks*32 + lg*8);
        }
        __builtin_amdgcn_s_setprio(1);
        #pragma unroll
        for (int ks = 0; ks < 4; ++ks) {
            frag8 hfk[4];
            #pragma unroll
            for (int m = 0; m < 4; ++m)
                hfk[m] = *reinterpret_cast<const frag8*>(&Hc[(m*16 + lr)*LDH + ks*32 + lg*8]);
            #pragma unroll
            for (int nt = 0; nt < 2; ++nt) {
                #pragma unroll
                for (int m = 0; m < 4; ++m)
                    acc2[nt][m] = __builtin_amdgcn_mfma_f32_16x16x32_bf16(hfk[m], w2f[nt][ks], acc2[nt][m], 0, 0, 0);
            }
        }
        __builtin_amdgcn_s_setprio(0);
    }
    // ---- t2 = t1 + mlp + bf2 (scatter to source coords)
    #pragma unroll
    for (int nt = 0; nt < 2; ++nt) {
        float bfv = bf2[w*32 + nt*16 + lr];
        #pragma unroll
        for (int m = 0; m < 4; ++m)
            #pragma unroll
            for (int r = 0; r < 4; ++r)
                t[(size_t)toks[m][r]*128 + w*32 + nt*16 + lr] = t1[nt][m][r] + acc2[nt][m][r] + bfv;
    }
}

// ---------------------------------------------------------------- K7: NHWC -> NCHW transpose
__global__ __launch_bounds__(256) void k_transpose(
    const float* __restrict__ t, float* __restrict__ out)
{
    __shared__ float tile[128][33];
    int blk = blockIdx.x;                 // 8 * 128 * 4
    int ct = blk & 3;
    int h  = (blk >> 2) & 127;
    int b  = blk >> 9;
    const float* src = t + ((size_t)b*16384 + (size_t)h*128)*128 + ct*32;
    #pragma unroll
    for (int q = 0; q < 16; ++q) {
        int idx = threadIdx.x + q*256;
        int w = idx >> 5, c = idx & 31;
        tile[w][c] = src[(size_t)w*128 + c];
    }
    __syncthreads();
    float* dst = out + ((size_t)(b*128 + ct*32))*16384 + (size_t)h*128;
    #pragma unroll
    for (int q = 0; q < 16; ++q) {
        int idx = threadIdx.x + q*256;
        int c = idx >> 7, w = idx & 127;
        dst[(size_t)c*16384 + w] = tile[w][c];
    }
}

// ----------------------------------------------------------------
extern "C" void kernel_launch(void* const* d_in, const int* in_sizes, int n_in,
                              void* d_out, int out_size, void* d_ws, size_t ws_size,
                              hipStream_t stream)
{
    const float* x  = (const float*)d_in[0];
    const float* Wm = (const float*)d_in[1];
    const float* bm = (const float*)d_in[2];

    float* t           = (float*)d_ws;                 // T x 128 f32 (64 MB)
    unsigned short* wb = (unsigned short*)(t + (size_t)Timg*128);

    unsigned short* Wmt = wb;                    // [128][256]
    unsigned short* Wqt[2], *Wot[2], *W1t[2], *W2t[2];
    unsigned short* p = wb + 32768;
    for (int i = 0; i < 2; ++i) {
        Wqt[i] = p; p += 36864;   // [288][128]
        Wot[i] = p; p += 12288;   // [128][96]
        W1t[i] = p; p += 65536;   // [512][128]
        W2t[i] = p; p += 65536;   // [128][512]
    }

    // ---- one launch for all 9 weight converts
    WcvtAll wa;
    int slot = 0;
    auto put = [&](const float* s, unsigned short* d, int R, int C, int q) {
        wa.src[slot] = s; wa.dst[slot] = d; wa.R[slot] = R; wa.C[slot] = C; wa.qrows[slot] = q; ++slot;
    };
    put(Wm, Wmt, 256, 128, 0);
    for (int i = 0; i < 2; ++i) {
        put((const float*)d_in[ 5 + i*12], Wqt[i], 128, 288, 96);  // fold SCALE into Q cols
        put((const float*)d_in[ 7 + i*12], Wot[i],  96, 128, 0);
        put((const float*)d_in[11 + i*12], W1t[i], 128, 512, 0);
        put((const float*)d_in[13 + i*12], W2t[i], 512, 128, 0);
    }
    k_wcvt_all<<<dim3(256, 9), 256, 0, stream>>>(wa, SCALE);

    k_patchmerge<<<Timg/64, 256, 0, stream>>>(x, Wmt, bm, t);

    for (int blk = 0; blk < 2; ++blk) {
        const float* g1  = (const float*)d_in[ 3 + blk*12];
        const float* b1  = (const float*)d_in[ 4 + blk*12];
        const float* pos = (const float*)d_in[ 6 + blk*12];
        const float* bo  = (const float*)d_in[ 8 + blk*12];
        const float* g2  = (const float*)d_in[ 9 + blk*12];
        const float* b2  = (const float*)d_in[10 + blk*12];
        const float* bf1 = (const float*)d_in[12 + blk*12];
        const float* bf2 = (const float*)d_in[14 + blk*12];

        k_block<<<2048, 256, 0, stream>>>(pos, t, g1, b1, Wqt[blk],
                                          Wot[blk], bo, g2, b2,
                                          W1t[blk], bf1, W2t[blk], bf2, blk);
    }

    k_transpose<<<8*128*4, 256, 0, stream>>>(t, (float*)d_out);
}